// Round 8
// baseline (205.434 us; speedup 1.0000x reference)
//
#include <hip/hip_runtime.h>
#include <hip/hip_cooperative_groups.h>

namespace cg = cooperative_groups;

// ---------------- problem constants ----------------
#define BATCH   8
#define LSEQ    1048576          // 1<<20
#define KCONV   500
#define TWIN    2097             // (L-K)/K + 1
#define MROWS   16776            // BATCH*TWIN
#define KDIM    4000             // KCONV * C_IN
#define NDIM    256              // 2 * C_OUT
#define COUT    128
#define VOCAB   257
#define VOCABP  256              // padding row of emb (zeros)

#define BMR     80               // m-rows per block (5 x 16)
#define NTILE   210              // ceil(MROWS/80): fits 256 CUs, 1 block/CU co-resident
#define SLABP   20               // positions per slab = 160 k = 5 BK32 iters
#define NSLAB   25
#define NG      125              // total BK32 iterations
#define PLANE   (NDIM * 32)      // 8192 shorts per g-plane of Wtf
#define AROWSH  168              // padded shorts per A-slab row (160 + 8)
#define STAGEN  (BMR * SLABP)    // 1600 gathers per slab
#define TSTRIDE 18               // shorts per emb-table entry (36B; r7 layout kept —
                                 // staggered staging hides the gather either way)

// ---------------- ws layout (bytes) ----------------
#define WTF_OFF   0ull
#define WTF_BYTES ((size_t)NG * PLANE * 2)                  // 2,048,000
#define POOL_OFF  (WTF_OFF + WTF_BYTES)                     // 1024 floats
#define CNT_OFF   (POOL_OFF + 4096)                         // 1 int

typedef __attribute__((ext_vector_type(8))) __bf16 bf16x8;
typedef __attribute__((ext_vector_type(4))) float  floatx4;

__device__ inline unsigned short f2bf(float f) {
    union { float f; unsigned u; } c; c.f = f;
    return (unsigned short)((c.u + 0x7FFFu + ((c.u >> 16) & 1u)) >> 16);
}
__device__ inline unsigned pack2(float lo, float hi) {
    return (unsigned)f2bf(lo) | ((unsigned)f2bf(hi) << 16);
}

// barrier that waits ONLY for LDS ops — leaves global (B/x prefetch) loads in flight
#define LDS_BARRIER() asm volatile("s_waitcnt lgkmcnt(0)\n\ts_barrier" ::: "memory")

// ---------------- single cooperative kernel ----------------
// ROUND 8 — LAUNCH-BOUNDARY REMOVAL. Cross-session data: non-gemm time is
// 97±3 us with 3 launches, 78±4 us with 2 -> ~19 us per kernel boundary.
// The wprep kernel is folded in: 210x512 threads distribute the 32,000 (n,g)
// weight-transform units (8x float4 reads + 4x uint4 writes each), zero
// pool/cnt, grid.sync() (cooperative launch; fences fire at kernel START on
// near-clean caches — NOT the r3 end-of-kernel eviction storm), then the r7
// GEMM body verbatim. The emb table + slab-0 staging don't depend on Wtf and
// are hoisted BEFORE grid.sync to overlap its latency; the first Wtf read
// (B prologue) is after it.
// GEMM body (verified r7): LDS emb-table gathers (36B stride), slab
// double-buffered, STAGGERED staging (gather-read at kt=l under that kt's
// MFMAs; write at kt=l+1 — lgkm in-order makes both free), compute-first
// ordering, frag-major Wtf with depth-2 register B prefetch (never drained
// by the lgkm-only LDS_BARRIER), x prefetched a slab ahead, fused head with
// relaxed device-scope sync (no cache-maintenance fences).
__global__ __launch_bounds__(512) void fused_kernel(const int* __restrict__ x,
                                                    const float* __restrict__ emb,
                                                    const float* __restrict__ w1,
                                                    const float* __restrict__ w2,
                                                    const float* __restrict__ b1,
                                                    const float* __restrict__ b2,
                                                    unsigned short* __restrict__ Wtf,
                                                    float* __restrict__ pool,
                                                    int* __restrict__ cnt,
                                                    const float* __restrict__ wd1,
                                                    const float* __restrict__ bd1,
                                                    const float* __restrict__ wd2,
                                                    const float* __restrict__ bd2,
                                                    float* __restrict__ out) {
    __shared__ __align__(16) unsigned short tableL[VOCAB * TSTRIDE]; // 9252 B
    __shared__ __align__(16) unsigned short As[2][BMR * AROWSH];     // 2 x 26.25 KB

    const int tid  = threadIdx.x;
    const int lane = tid & 63;
    const int wv   = tid >> 6;                         // 0..7
    const int m0   = blockIdx.x * BMR;
    const int r16  = lane & 15;
    const int q    = lane >> 4;                        // 0..3

    // ================= phase 0: distributed weight prep =================
    // unit (n,g): Wtf[g][n][kk] = f2bf(w_n[e=(kk&7)][p=g*4+(kk>>3)]),
    // i.e. 8 aligned float4 reads (e*500+g*4) and one 64B store.
    {
        const int gtid = blockIdx.x * 512 + tid;       // 0..107519
        if (gtid < NDIM * NG) {                        // 32000 units, single shot
            const int n = gtid / NG;                   // 0..255
            const int g = gtid - n * NG;               // 0..124
            const float* src = (n < COUT) ? (w1 + (size_t)n * KDIM)
                                          : (w2 + (size_t)(n - COUT) * KDIM);
            unsigned short o16[32];
#pragma unroll
            for (int e = 0; e < 8; ++e) {
                float4 v = *(const float4*)(src + e * KCONV + g * 4);
                o16[e +  0] = f2bf(v.x);
                o16[e +  8] = f2bf(v.y);
                o16[e + 16] = f2bf(v.z);
                o16[e + 24] = f2bf(v.w);
            }
            uint4* dst = (uint4*)(Wtf + (size_t)g * PLANE + n * 32);
            const uint4* s4 = (const uint4*)o16;
            dst[0] = s4[0]; dst[1] = s4[1]; dst[2] = s4[2]; dst[3] = s4[3];
        }
        if (gtid < 256) ((float4*)pool)[gtid] = float4{0.f, 0.f, 0.f, 0.f};
        if (gtid == 0) *cnt = 0;
    }

    // ======= pre-sync work that does NOT depend on Wtf (overlaps sync) =======
    // ---- build bf16 emb table in LDS (36B stride) ----
    if (tid < VOCAB) {
        const float4* er = (const float4*)(emb + tid * 8);
        float4 a = er[0], b = er[1];
        unsigned* tb = (unsigned*)(tableL + tid * TSTRIDE);
        tb[0] = pack2(a.x, a.y); tb[1] = pack2(a.z, a.w);
        tb[2] = pack2(b.x, b.y); tb[3] = pack2(b.z, b.w);
    }

    // ---- staging roles: thread handles idx = tid + 512*l (idx < 1600) ----
    const int* xptr[4];
    int        loff[4];
    bool       sval[4];
    bool       sact[4];
#pragma unroll
    for (int l = 0; l < 4; ++l) {
        sact[l] = (l < 3) || (tid < STAGEN - 3 * 512);  // slot 3: tids 0..63 only
        int idx = tid + 512 * l;
        sval[l] = (idx < STAGEN);
        int ic  = sval[l] ? idx : 0;
        int row = ic / SLABP;
        int pos = ic - row * SLABP;
        int am  = m0 + row;
        bool av = sval[l] && (am < MROWS);
        sval[l] = av;
        int amc = av ? am : 0;
        int b   = amc / TWIN;
        int t   = amc - b * TWIN;
        xptr[l] = x + ((size_t)b * LSEQ + (size_t)t * KCONV + pos);
        loff[l] = row * AROWSH + pos * 8;
    }

    // ---- compute role ----
    const int o = wv * 16 + r16;                       // 0..127
    const size_t boff0 = (size_t)o * 32 + q * 8;
    const size_t boff1 = (size_t)(o + 128) * 32 + q * 8;

    floatx4 acc[5][2];
#pragma unroll
    for (int i = 0; i < 5; ++i) { acc[i][0] = floatx4{0,0,0,0}; acc[i][1] = floatx4{0,0,0,0}; }

    // ---- x values for slab 0 ----
    int xv[4], xn[4];
#pragma unroll
    for (int l = 0; l < 4; ++l) xv[l] = sval[l] ? xptr[l][0] : VOCABP;
    __syncthreads();                                   // table visible

    // ---- stage slab 0 into buf 0 ----
#pragma unroll
    for (int l = 0; l < 4; ++l) {
        if (sact[l]) {
            const unsigned* gb = (const unsigned*)(tableL + xv[l] * TSTRIDE);
            uint4 g; g.x = gb[0]; g.y = gb[1]; g.z = gb[2]; g.w = gb[3];
            *(uint4*)((unsigned short*)As + loff[l]) = g;
        }
    }
#pragma unroll
    for (int l = 0; l < 4; ++l) xv[l] = sval[l] ? xptr[l][SLABP] : VOCABP;
    LDS_BARRIER();

    // ================= grid-wide sync: Wtf now visible =================
    cg::this_grid().sync();

    // ---- B prefetch prologue: g=0,1 (first Wtf reads) ----
    bf16x8 bc0[2], bc1[2], bc2[2] = {};
    bc0[0] = *(const bf16x8*)(Wtf + boff0);
    bc0[1] = *(const bf16x8*)(Wtf + boff1);
    bc1[0] = *(const bf16x8*)(Wtf + PLANE + boff0);
    bc1[1] = *(const bf16x8*)(Wtf + PLANE + boff1);

    int buf = 0;
    for (int s = 0; s < NSLAB; ++s) {
        // issue x loads for slab s+2 early (vmcnt; a full slab of cover)
        if (s + 2 < NSLAB) {
#pragma unroll
            for (int l = 0; l < 4; ++l)
                xn[l] = sval[l] ? xptr[l][(s + 2) * SLABP] : VOCABP;
        }

        const unsigned short* Asb  = (const unsigned short*)As + buf * (BMR * AROWSH);
        unsigned short*       dstS = (unsigned short*)As + (buf ^ 1) * (BMR * AROWSH);
        const bool stg = (s + 1 < NSLAB);
        uint4 gr[4];

        // ---- 5 BK=32 iterations; B depth-2 register pipeline; staged gathers ----
#pragma unroll
        for (int kt = 0; kt < 5; ++kt) {
            const int g = s * 5 + kt;
            if (g + 2 < NG) {
                const unsigned short* Wp = Wtf + (size_t)(g + 2) * PLANE;
                bc2[0] = *(const bf16x8*)(Wp + boff0);
                bc2[1] = *(const bf16x8*)(Wp + boff1);
            }
            bf16x8 af[5];
#pragma unroll
            for (int i = 0; i < 5; ++i)
                af[i] = *(const bf16x8*)(Asb + (i * 16 + r16) * AROWSH + (kt * 4 + q) * 8);

            // gather-READ slot kt: issued with this kt's af reads; the MFMA's
            // counted lgkm wait only needs af, leaving these outstanding.
            if (kt < 4 && stg && sact[kt]) {
                const unsigned* gb = (const unsigned*)(tableL + xv[kt] * TSTRIDE);
                gr[kt].x = gb[0]; gr[kt].y = gb[1]; gr[kt].z = gb[2]; gr[kt].w = gb[3];
            }

#pragma unroll
            for (int i = 0; i < 5; ++i) {
                acc[i][0] = __builtin_amdgcn_mfma_f32_16x16x32_bf16(af[i], bc0[0], acc[i][0], 0, 0, 0);
                acc[i][1] = __builtin_amdgcn_mfma_f32_16x16x32_bf16(af[i], bc0[1], acc[i][1], 0, 0, 0);
            }
            bc0[0] = bc1[0]; bc0[1] = bc1[1];
            bc1[0] = bc2[0]; bc1[1] = bc2[1];

            // gather-WRITE slot kt-1: data arrived a full kt ago -> no stall.
            if (kt >= 1 && stg && sact[kt - 1])
                *(uint4*)(dstS + loff[kt - 1]) = gr[kt - 1];
        }
#pragma unroll
        for (int l = 0; l < 4; ++l) xv[l] = xn[l];
        LDS_BARRIER();
        buf ^= 1;
    }

    // ---- epilogue: gate + per-batch max in registers, atomicMax flush ----
    // C/D layout: col = lane&15 (n), row = q*4 + reg (m).
    const float b1v = b1[o], b2v = b2[o];
    float cur = 0.0f;
    int curb  = (m0 + q * 4) / TWIN;
#pragma unroll
    for (int i = 0; i < 5; ++i) {
#pragma unroll
        for (int rg = 0; rg < 4; ++rg) {
            const int row = m0 + i * 16 + q * 4 + rg;
            if (row < MROWS) {
                const int bb = row / TWIN;
                if (bb != curb) {
                    atomicMax((int*)&pool[curb * COUT + o], __float_as_int(cur));
                    cur = 0.0f; curb = bb;
                }
                const float c1 = acc[i][0][rg] + b1v;
                const float c2 = acc[i][1][rg] + b2v;
                const float g  = fmaxf(c1, 0.0f) / (1.0f + __expf(-c2));
                cur = fmaxf(cur, g);
            }
        }
    }
    atomicMax((int*)&pool[curb * COUT + o], __float_as_int(cur));

    // ---- fused head: last block to finish does the dense layers ----
    // Drain this wave's device-scope atomics, barrier so all waves' atomics
    // are complete, then relaxed counter (no cache-maintenance fences).
    asm volatile("s_waitcnt vmcnt(0)" ::: "memory");
    __syncthreads();
    __shared__ int lastFlag;
    if (tid == 0) {
        int prev = __hip_atomic_fetch_add(cnt, 1, __ATOMIC_RELAXED, __HIP_MEMORY_SCOPE_AGENT);
        lastFlag = (prev == NTILE - 1) ? 1 : 0;
    }
    __syncthreads();
    if (!lastFlag) return;

    // reuse As as scratch: poolL[1024] + red[8][128]
    float* poolL = (float*)As;
    float* red   = poolL + BATCH * COUT;
    // agent-scope per-access loads: coherent view of the atomicMax results
    poolL[tid] = __int_as_float(
        __hip_atomic_load((int*)&pool[tid], __ATOMIC_RELAXED, __HIP_MEMORY_SCOPE_AGENT));
    poolL[tid + 512] = __int_as_float(
        __hip_atomic_load((int*)&pool[tid + 512], __ATOMIC_RELAXED, __HIP_MEMORY_SCOPE_AGENT));
    __syncthreads();

    if (tid < COUT) {
        const int j = tid;
        const float wj = wd2[j];
#pragma unroll
        for (int b = 0; b < BATCH; ++b) {
            float s = bd1[j];
            for (int i = 0; i < COUT; ++i) s += poolL[b * COUT + i] * wd1[j * COUT + i];
            red[b * COUT + j] = fmaxf(s, 0.0f) * wj;
        }
    }
    __syncthreads();
    if (tid < BATCH) {
        float s = 0.0f;
        for (int i = 0; i < COUT; ++i) s += red[tid * COUT + i];
        out[tid] = 1.0f / (1.0f + expf(-(s + bd2[0])));
    }
}

// ---------------- launch ----------------
extern "C" void kernel_launch(void* const* d_in, const int* in_sizes, int n_in,
                              void* d_out, int out_size, void* d_ws, size_t ws_size,
                              hipStream_t stream) {
    const int*   x   = (const int*)d_in[0];
    const float* emb = (const float*)d_in[1];
    const float* w1  = (const float*)d_in[2];
    const float* b1  = (const float*)d_in[3];
    const float* w2  = (const float*)d_in[4];
    const float* b2  = (const float*)d_in[5];
    const float* wd1 = (const float*)d_in[6];
    const float* bd1 = (const float*)d_in[7];
    const float* wd2 = (const float*)d_in[8];
    const float* bd2 = (const float*)d_in[9];
    float* out = (float*)d_out;

    unsigned short* Wtf  = (unsigned short*)((char*)d_ws + WTF_OFF);
    float*          pool = (float*)((char*)d_ws + POOL_OFF);
    int*            cnt  = (int*)((char*)d_ws + CNT_OFF);

    void* args[] = { (void*)&x, (void*)&emb, (void*)&w1, (void*)&w2,
                     (void*)&b1, (void*)&b2, (void*)&Wtf, (void*)&pool,
                     (void*)&cnt, (void*)&wd1, (void*)&bd1, (void*)&wd2,
                     (void*)&bd2, (void*)&out };
    hipLaunchCooperativeKernel((const void*)fused_kernel, dim3(NTILE), dim3(512),
                               args, 0, stream);
}

// Round 9
// 190.593 us; speedup vs baseline: 1.0779x; 1.0779x over previous
//
#include <hip/hip_runtime.h>

// ---------------- problem constants ----------------
#define BATCH   8
#define LSEQ    1048576          // 1<<20
#define KCONV   500
#define TWIN    2097             // (L-K)/K + 1
#define MROWS   16776            // BATCH*TWIN
#define KDIM    4000             // KCONV * C_IN
#define NDIM    256              // 2 * C_OUT
#define COUT    128
#define VOCAB   257
#define VOCABP  256              // padding row of emb (zeros)

#define BMR     80               // m-rows per block (5 x 16)
#define NTILE   210              // ceil(MROWS/80): fits 256 CUs, 1 block/CU
#define SLABP   20               // positions per slab = 160 k = 5 BK32 iters
#define NSLAB   25
#define NG      125              // total BK32 iterations
#define PLANE   (NDIM * 32)      // 8192 shorts per g-plane of Wtf
#define AROWSH  168              // padded shorts per A-slab row (160 + 8)
#define STAGEN  (BMR * SLABP)    // 1600 gathers per slab

// ---------------- ws layout (bytes) ----------------
#define WTF_OFF   0ull
#define WTF_BYTES ((size_t)NG * PLANE * 2)                  // 2,048,000
#define POOL_OFF  (WTF_OFF + WTF_BYTES)                     // 1024 floats
#define CNT_OFF   (POOL_OFF + 4096)                         // 1 int

typedef __attribute__((ext_vector_type(8))) __bf16 bf16x8;
typedef __attribute__((ext_vector_type(4))) float  floatx4;

__device__ inline unsigned short f2bf(float f) {
    union { float f; unsigned u; } c; c.f = f;
    return (unsigned short)((c.u + 0x7FFFu + ((c.u >> 16) & 1u)) >> 16);
}
__device__ inline unsigned pack2(float lo, float hi) {
    return (unsigned)f2bf(lo) | ((unsigned)f2bf(hi) << 16);
}

// barrier that waits ONLY for LDS ops — leaves global (B/x prefetch) loads in flight
#define LDS_BARRIER() asm volatile("s_waitcnt lgkmcnt(0)\n\ts_barrier" ::: "memory")

// ---------------- kernel 1: frag-major weights + zero pool/counter ----------------
// Wtf[g][n][kk] = w_n[e=(g*32+kk)&7][p=(g*32+kk)>>3]
__global__ __launch_bounds__(256) void wprep_kernel(const float* __restrict__ w1,
                                                    const float* __restrict__ w2,
                                                    unsigned short* __restrict__ Wtf,
                                                    float* __restrict__ pool,
                                                    int* __restrict__ cnt) {
    const int n   = blockIdx.x;                        // 0..255
    const int tid = threadIdx.x;
    __shared__ float tile[KDIM];                       // 16 KB
    const float* src = (n < COUT) ? (w1 + (size_t)n * KDIM)
                                  : (w2 + (size_t)(n - COUT) * KDIM);
    for (int i = tid; i < KDIM; i += 256) tile[i] = src[i];
    __syncthreads();
    for (int i = tid; i < KDIM; i += 256) {
        int g = i >> 5, kk = i & 31;
        Wtf[(size_t)g * PLANE + n * 32 + kk] = f2bf(tile[(i & 7) * KCONV + (i >> 3)]);
    }
    if (n == 0) {
        if (tid < 256) ((float4*)pool)[tid] = float4{0.f, 0.f, 0.f, 0.f};
        if (tid == 0) *cnt = 0;
    }
}

// ---------------- kernel 2: fused embed + full-K GEMM + gate + max-pool + head ----------------
// ROUND 9 (on the verified r7 base; r8's cooperative fold reverted — grid.sync
// cost ~25us in-kernel and the cooperative launch path itself ~+35us runtime):
// (a) TABLE STRIDE BACK TO 16B: r7's 36B stride split each gather into 4x
//     ds_read_b32 and RAISED conflicts 5.4M->6.67M. Single b128 gather again.
// (b) A-FRAGMENT DEPTH-2 PIPELINE: af reads for kt+1 issue during kt's MFMAs
//     (fresh load only at each slab's kt0, after the barrier). Previously every
//     kt's first MFMA waited ~120cy on its own 5 ds_read_b128s; now 4/5 kts
//     have reads issued a full kt (~10 MFMAs) earlier. Attacks the in-period
//     dependency residue that r5/r6 proved isn't occupancy or barrier count.
// Retained from r7: STAGGERED STAGING (gather-read at kt=l under MFMAs,
// write at kt=l+1; lgkm in-order makes both free), compute-first ordering,
// frag-major Wtf depth-2 register B prefetch (never drained by the lgkm-only
// LDS_BARRIER), x prefetched a slab ahead, fused head with relaxed
// device-scope sync (no cache-maintenance fences — r3's cost ~45us).
__global__ __launch_bounds__(512) void gemm_kernel(const int* __restrict__ x,
                                                   const float* __restrict__ emb,
                                                   const unsigned short* __restrict__ Wtf,
                                                   const float* __restrict__ b1,
                                                   const float* __restrict__ b2,
                                                   float* __restrict__ pool,
                                                   int* __restrict__ cnt,
                                                   const float* __restrict__ wd1,
                                                   const float* __restrict__ bd1,
                                                   const float* __restrict__ wd2,
                                                   const float* __restrict__ bd2,
                                                   float* __restrict__ out) {
    __shared__ __align__(16) unsigned short tableL[VOCAB * 8];   // 4112 B
    __shared__ __align__(16) unsigned short As[2][BMR * AROWSH]; // 2 x 26.25 KB

    const int tid  = threadIdx.x;
    const int lane = tid & 63;
    const int wv   = tid >> 6;                         // 0..7
    const int m0   = blockIdx.x * BMR;
    const int r16  = lane & 15;
    const int q    = lane >> 4;                        // 0..3

    // ---- build bf16 emb table in LDS (16B entries) ----
    if (tid < VOCAB) {
        const float4* er = (const float4*)(emb + tid * 8);
        float4 a = er[0], b = er[1];
        uint4 u;
        u.x = pack2(a.x, a.y); u.y = pack2(a.z, a.w);
        u.z = pack2(b.x, b.y); u.w = pack2(b.z, b.w);
        *(uint4*)(tableL + tid * 8) = u;
    }

    // ---- staging roles: thread handles idx = tid + 512*l (idx < 1600) ----
    const int* xptr[4];
    int        loff[4];
    bool       sval[4];
    bool       sact[4];
#pragma unroll
    for (int l = 0; l < 4; ++l) {
        sact[l] = (l < 3) || (tid < STAGEN - 3 * 512);  // slot 3: tids 0..63 only
        int idx = tid + 512 * l;
        sval[l] = (idx < STAGEN);
        int ic  = sval[l] ? idx : 0;
        int row = ic / SLABP;
        int pos = ic - row * SLABP;
        int am  = m0 + row;
        bool av = sval[l] && (am < MROWS);
        sval[l] = av;
        int amc = av ? am : 0;
        int b   = amc / TWIN;
        int t   = amc - b * TWIN;
        xptr[l] = x + ((size_t)b * LSEQ + (size_t)t * KCONV + pos);
        loff[l] = row * AROWSH + pos * 8;
    }

    // ---- compute role ----
    const int o = wv * 16 + r16;                       // 0..127
    const size_t boff0 = (size_t)o * 32 + q * 8;
    const size_t boff1 = (size_t)(o + 128) * 32 + q * 8;

    floatx4 acc[5][2];
#pragma unroll
    for (int i = 0; i < 5; ++i) { acc[i][0] = floatx4{0,0,0,0}; acc[i][1] = floatx4{0,0,0,0}; }

    // ---- x values for slab 0 ----
    int xv[4], xn[4];
#pragma unroll
    for (int l = 0; l < 4; ++l) xv[l] = sval[l] ? xptr[l][0] : VOCABP;
    __syncthreads();                                   // table visible

    // ---- stage slab 0 into buf 0 (unavoidable burst before first compute) ----
#pragma unroll
    for (int l = 0; l < 4; ++l) {
        if (sact[l]) {
            uint4 g = *(const uint4*)(tableL + xv[l] * 8);
            *(uint4*)((unsigned short*)As + loff[l]) = g;
        }
    }
#pragma unroll
    for (int l = 0; l < 4; ++l) xv[l] = sval[l] ? xptr[l][SLABP] : VOCABP;
    LDS_BARRIER();

    // ---- B prefetch prologue: g=0,1 ----
    bf16x8 bc0[2], bc1[2], bc2[2] = {};
    bc0[0] = *(const bf16x8*)(Wtf + boff0);
    bc0[1] = *(const bf16x8*)(Wtf + boff1);
    bc1[0] = *(const bf16x8*)(Wtf + PLANE + boff0);
    bc1[1] = *(const bf16x8*)(Wtf + PLANE + boff1);

    int buf = 0;
    for (int s = 0; s < NSLAB; ++s) {
        // issue x loads for slab s+2 early (vmcnt; a full slab of cover)
        if (s + 2 < NSLAB) {
#pragma unroll
            for (int l = 0; l < 4; ++l)
                xn[l] = sval[l] ? xptr[l][(s + 2) * SLABP] : VOCABP;
        }

        const unsigned short* Asb  = (const unsigned short*)As + buf * (BMR * AROWSH);
        unsigned short*       dstS = (unsigned short*)As + (buf ^ 1) * (BMR * AROWSH);
        const bool stg = (s + 1 < NSLAB);
        uint4 gr[4];

        // ---- af depth-2: fresh load of kt=0 fragments (right after barrier) ----
        bf16x8 afc[5];
#pragma unroll
        for (int i = 0; i < 5; ++i)
            afc[i] = *(const bf16x8*)(Asb + (i * 16 + r16) * AROWSH + q * 8);

        // ---- 5 BK=32 iterations; A depth-2 + B depth-2 pipelines; staged gathers ----
#pragma unroll
        for (int kt = 0; kt < 5; ++kt) {
            const int g = s * 5 + kt;
            if (g + 2 < NG) {
                const unsigned short* Wp = Wtf + (size_t)(g + 2) * PLANE;
                bc2[0] = *(const bf16x8*)(Wp + boff0);
                bc2[1] = *(const bf16x8*)(Wp + boff1);
            }

            // af prefetch for kt+1 (issued before this kt's MFMAs; MFMAs use afc
            // already in registers, so the counted lgkm wait lands a kt later)
            bf16x8 afn[5];
            if (kt < 4) {
#pragma unroll
                for (int i = 0; i < 5; ++i)
                    afn[i] = *(const bf16x8*)(Asb + (i * 16 + r16) * AROWSH
                                              + ((kt + 1) * 4 + q) * 8);
            }

            // gather-READ slot kt: single b128 from the 16B-stride table
            if (kt < 4 && stg && sact[kt])
                gr[kt] = *(const uint4*)(tableL + xv[kt] * 8);

#pragma unroll
            for (int i = 0; i < 5; ++i) {
                acc[i][0] = __builtin_amdgcn_mfma_f32_16x16x32_bf16(afc[i], bc0[0], acc[i][0], 0, 0, 0);
                acc[i][1] = __builtin_amdgcn_mfma_f32_16x16x32_bf16(afc[i], bc0[1], acc[i][1], 0, 0, 0);
            }
            bc0[0] = bc1[0]; bc0[1] = bc1[1];
            bc1[0] = bc2[0]; bc1[1] = bc2[1];

            // gather-WRITE slot kt-1: data arrived a full kt ago -> no stall
            if (kt >= 1 && stg && sact[kt - 1])
                *(uint4*)(dstS + loff[kt - 1]) = gr[kt - 1];

            if (kt < 4) {
#pragma unroll
                for (int i = 0; i < 5; ++i) afc[i] = afn[i];
            }
        }
#pragma unroll
        for (int l = 0; l < 4; ++l) xv[l] = xn[l];
        LDS_BARRIER();
        buf ^= 1;
    }

    // ---- epilogue: gate + per-batch max in registers, atomicMax flush ----
    // C/D layout: col = lane&15 (n), row = q*4 + reg (m).
    const float b1v = b1[o], b2v = b2[o];
    float cur = 0.0f;
    int curb  = (m0 + q * 4) / TWIN;
#pragma unroll
    for (int i = 0; i < 5; ++i) {
#pragma unroll
        for (int rg = 0; rg < 4; ++rg) {
            const int row = m0 + i * 16 + q * 4 + rg;
            if (row < MROWS) {
                const int bb = row / TWIN;
                if (bb != curb) {
                    atomicMax((int*)&pool[curb * COUT + o], __float_as_int(cur));
                    cur = 0.0f; curb = bb;
                }
                const float c1 = acc[i][0][rg] + b1v;
                const float c2 = acc[i][1][rg] + b2v;
                const float g  = fmaxf(c1, 0.0f) / (1.0f + __expf(-c2));
                cur = fmaxf(cur, g);
            }
        }
    }
    atomicMax((int*)&pool[curb * COUT + o], __float_as_int(cur));

    // ---- fused head: last block to finish does the dense layers ----
    asm volatile("s_waitcnt vmcnt(0)" ::: "memory");
    __syncthreads();
    __shared__ int lastFlag;
    if (tid == 0) {
        int prev = __hip_atomic_fetch_add(cnt, 1, __ATOMIC_RELAXED, __HIP_MEMORY_SCOPE_AGENT);
        lastFlag = (prev == NTILE - 1) ? 1 : 0;
    }
    __syncthreads();
    if (!lastFlag) return;

    // reuse As as scratch: poolL[1024] + red[8][128]
    float* poolL = (float*)As;
    float* red   = poolL + BATCH * COUT;
    poolL[tid] = __int_as_float(
        __hip_atomic_load((int*)&pool[tid], __ATOMIC_RELAXED, __HIP_MEMORY_SCOPE_AGENT));
    poolL[tid + 512] = __int_as_float(
        __hip_atomic_load((int*)&pool[tid + 512], __ATOMIC_RELAXED, __HIP_MEMORY_SCOPE_AGENT));
    __syncthreads();

    if (tid < COUT) {
        const int j = tid;
        const float wj = wd2[j];
#pragma unroll
        for (int b = 0; b < BATCH; ++b) {
            float s = bd1[j];
            for (int i = 0; i < COUT; ++i) s += poolL[b * COUT + i] * wd1[j * COUT + i];
            red[b * COUT + j] = fmaxf(s, 0.0f) * wj;
        }
    }
    __syncthreads();
    if (tid < BATCH) {
        float s = 0.0f;
        for (int i = 0; i < COUT; ++i) s += red[tid * COUT + i];
        out[tid] = 1.0f / (1.0f + expf(-(s + bd2[0])));
    }
}

// ---------------- launch ----------------
extern "C" void kernel_launch(void* const* d_in, const int* in_sizes, int n_in,
                              void* d_out, int out_size, void* d_ws, size_t ws_size,
                              hipStream_t stream) {
    const int*   x   = (const int*)d_in[0];
    const float* emb = (const float*)d_in[1];
    const float* w1  = (const float*)d_in[2];
    const float* b1  = (const float*)d_in[3];
    const float* w2  = (const float*)d_in[4];
    const float* b2  = (const float*)d_in[5];
    const float* wd1 = (const float*)d_in[6];
    const float* bd1 = (const float*)d_in[7];
    const float* wd2 = (const float*)d_in[8];
    const float* bd2 = (const float*)d_in[9];
    float* out = (float*)d_out;

    unsigned short* Wtf  = (unsigned short*)((char*)d_ws + WTF_OFF);
    float*          pool = (float*)((char*)d_ws + POOL_OFF);
    int*            cnt  = (int*)((char*)d_ws + CNT_OFF);

    wprep_kernel<<<dim3(NDIM), dim3(256), 0, stream>>>(w1, w2, Wtf, pool, cnt);
    gemm_kernel<<<dim3(NTILE), dim3(512), 0, stream>>>(x, emb, Wtf, b1, b2, pool, cnt,
                                                       wd1, bd1, wd2, bd2, out);
}

// Round 10
// 159.436 us; speedup vs baseline: 1.2885x; 1.1954x over previous
//
#include <hip/hip_runtime.h>

// ---------------- problem constants ----------------
#define BATCH   8
#define LSEQ    1048576          // 1<<20
#define KCONV   500
#define TWIN    2097             // (L-K)/K + 1
#define MROWS   16776            // BATCH*TWIN
#define KDIM    4000             // KCONV * C_IN
#define NDIM    256              // 2 * C_OUT
#define COUT    128
#define VOCAB   257
#define VOCABP  256              // padding row of emb (zeros)

#define BMR     80               // m-rows per block (5 x 16)
#define NTILE   210              // ceil(MROWS/80): fits 256 CUs, 1 block/CU
#define SLABP   20               // positions per slab = 160 k = 5 BK32 iters
#define NSLAB   25
#define NG      125              // total BK32 iterations
#define PLANE   (NDIM * 32)      // 8192 shorts per g-plane of Wtf
#define AROWSH  168              // padded shorts per A-slab row (160 + 8)
#define STAGEN  (BMR * SLABP)    // 1600 gathers per slab

// ---------------- ws layout (bytes) ----------------
#define WTF_OFF   0ull
#define WTF_BYTES ((size_t)NG * PLANE * 2)                  // 2,048,000
#define POOL_OFF  (WTF_OFF + WTF_BYTES)                     // 1024 floats
#define CNT_OFF   (POOL_OFF + 4096)                         // 1 int

typedef __attribute__((ext_vector_type(8))) __bf16 bf16x8;
typedef __attribute__((ext_vector_type(4))) float  floatx4;

__device__ inline unsigned short f2bf(float f) {
    union { float f; unsigned u; } c; c.f = f;
    return (unsigned short)((c.u + 0x7FFFu + ((c.u >> 16) & 1u)) >> 16);
}
__device__ inline unsigned pack2(float lo, float hi) {
    return (unsigned)f2bf(lo) | ((unsigned)f2bf(hi) << 16);
}

// barrier that waits ONLY for LDS ops — leaves global (B/x prefetch) loads in flight
#define LDS_BARRIER() asm volatile("s_waitcnt lgkmcnt(0)\n\ts_barrier" ::: "memory")

// ---------------- kernel 1: frag-major weights + zero pool/counter ----------------
// Wtf[g][n][kk] = w_n[e=(g*32+kk)&7][p=(g*32+kk)>>3]
__global__ __launch_bounds__(256) void wprep_kernel(const float* __restrict__ w1,
                                                    const float* __restrict__ w2,
                                                    unsigned short* __restrict__ Wtf,
                                                    float* __restrict__ pool,
                                                    int* __restrict__ cnt) {
    const int n   = blockIdx.x;                        // 0..255
    const int tid = threadIdx.x;
    __shared__ float tile[KDIM];                       // 16 KB
    const float* src = (n < COUT) ? (w1 + (size_t)n * KDIM)
                                  : (w2 + (size_t)(n - COUT) * KDIM);
    for (int i = tid; i < KDIM; i += 256) tile[i] = src[i];
    __syncthreads();
    for (int i = tid; i < KDIM; i += 256) {
        int g = i >> 5, kk = i & 31;
        Wtf[(size_t)g * PLANE + n * 32 + kk] = f2bf(tile[(i & 7) * KCONV + (i >> 3)]);
    }
    if (n == 0) {
        if (tid < 256) ((float4*)pool)[tid] = float4{0.f, 0.f, 0.f, 0.f};
        if (tid == 0) *cnt = 0;
    }
}

// ---------------- kernel 2: fused embed + full-K GEMM + gate + max-pool + head ----------------
// ROUND 10 — the unconfounded combination of the two verified wins:
//   r7's STAGGERED STAGING (gather-read at kt=l issued under that kt's MFMAs;
//   gather-write at kt=l+1, a full kt after its read — lgkm in-order makes
//   both free) + 16B TABLE ENTRIES (single ds_read_b128 gather; r7's 36B
//   stride split gathers into 4x ds_read_b32 and RAISED conflicts to 6.67M).
// r9's af depth-2 pipeline is REMOVED: its +40 live VGPRs spilled to scratch
// (WRITE_SIZE 0.76 -> 8.3MB, gemm 82 -> 119us). Register budget restored to
// the r7 level (~72); spill signature must vanish.
// Retained: compute-first ordering, frag-major Wtf depth-2 register B
// prefetch (never drained by the lgkm-only LDS_BARRIER), x prefetched a slab
// ahead on vmcnt, fused head with relaxed device-scope sync (no
// cache-maintenance fences — the r3 variant cost ~45us in L2 writebacks).
__global__ __launch_bounds__(512) void gemm_kernel(const int* __restrict__ x,
                                                   const float* __restrict__ emb,
                                                   const unsigned short* __restrict__ Wtf,
                                                   const float* __restrict__ b1,
                                                   const float* __restrict__ b2,
                                                   float* __restrict__ pool,
                                                   int* __restrict__ cnt,
                                                   const float* __restrict__ wd1,
                                                   const float* __restrict__ bd1,
                                                   const float* __restrict__ wd2,
                                                   const float* __restrict__ bd2,
                                                   float* __restrict__ out) {
    __shared__ __align__(16) unsigned short tableL[VOCAB * 8];   // 4112 B
    __shared__ __align__(16) unsigned short As[2][BMR * AROWSH]; // 2 x 26.25 KB

    const int tid  = threadIdx.x;
    const int lane = tid & 63;
    const int wv   = tid >> 6;                         // 0..7
    const int m0   = blockIdx.x * BMR;
    const int r16  = lane & 15;
    const int q    = lane >> 4;                        // 0..3

    // ---- build bf16 emb table in LDS (16B entries) ----
    if (tid < VOCAB) {
        const float4* er = (const float4*)(emb + tid * 8);
        float4 a = er[0], b = er[1];
        uint4 u;
        u.x = pack2(a.x, a.y); u.y = pack2(a.z, a.w);
        u.z = pack2(b.x, b.y); u.w = pack2(b.z, b.w);
        *(uint4*)(tableL + tid * 8) = u;
    }

    // ---- staging roles: thread handles idx = tid + 512*l (idx < 1600) ----
    const int* xptr[4];
    int        loff[4];
    bool       sval[4];
    bool       sact[4];
#pragma unroll
    for (int l = 0; l < 4; ++l) {
        sact[l] = (l < 3) || (tid < STAGEN - 3 * 512);  // slot 3: tids 0..63 only
        int idx = tid + 512 * l;
        sval[l] = (idx < STAGEN);
        int ic  = sval[l] ? idx : 0;
        int row = ic / SLABP;
        int pos = ic - row * SLABP;
        int am  = m0 + row;
        bool av = sval[l] && (am < MROWS);
        sval[l] = av;
        int amc = av ? am : 0;
        int b   = amc / TWIN;
        int t   = amc - b * TWIN;
        xptr[l] = x + ((size_t)b * LSEQ + (size_t)t * KCONV + pos);
        loff[l] = row * AROWSH + pos * 8;
    }

    // ---- compute role ----
    const int o = wv * 16 + r16;                       // 0..127
    const size_t boff0 = (size_t)o * 32 + q * 8;
    const size_t boff1 = (size_t)(o + 128) * 32 + q * 8;

    floatx4 acc[5][2];
#pragma unroll
    for (int i = 0; i < 5; ++i) { acc[i][0] = floatx4{0,0,0,0}; acc[i][1] = floatx4{0,0,0,0}; }

    // ---- x values for slab 0 ----
    int xv[4], xn[4];
#pragma unroll
    for (int l = 0; l < 4; ++l) xv[l] = sval[l] ? xptr[l][0] : VOCABP;
    __syncthreads();                                   // table visible

    // ---- stage slab 0 into buf 0 (unavoidable burst before first compute) ----
#pragma unroll
    for (int l = 0; l < 4; ++l) {
        if (sact[l]) {
            uint4 g = *(const uint4*)(tableL + xv[l] * 8);
            *(uint4*)((unsigned short*)As + loff[l]) = g;
        }
    }
#pragma unroll
    for (int l = 0; l < 4; ++l) xv[l] = sval[l] ? xptr[l][SLABP] : VOCABP;
    LDS_BARRIER();

    // ---- B prefetch prologue: g=0,1 ----
    bf16x8 bc0[2], bc1[2], bc2[2] = {};
    bc0[0] = *(const bf16x8*)(Wtf + boff0);
    bc0[1] = *(const bf16x8*)(Wtf + boff1);
    bc1[0] = *(const bf16x8*)(Wtf + PLANE + boff0);
    bc1[1] = *(const bf16x8*)(Wtf + PLANE + boff1);

    int buf = 0;
    for (int s = 0; s < NSLAB; ++s) {
        // issue x loads for slab s+2 early (vmcnt; a full slab of cover)
        if (s + 2 < NSLAB) {
#pragma unroll
            for (int l = 0; l < 4; ++l)
                xn[l] = sval[l] ? xptr[l][(s + 2) * SLABP] : VOCABP;
        }

        const unsigned short* Asb  = (const unsigned short*)As + buf * (BMR * AROWSH);
        unsigned short*       dstS = (unsigned short*)As + (buf ^ 1) * (BMR * AROWSH);
        const bool stg = (s + 1 < NSLAB);
        uint4 gr[4];

        // ---- 5 BK=32 iterations; B depth-2 register pipeline; staged gathers ----
#pragma unroll
        for (int kt = 0; kt < 5; ++kt) {
            const int g = s * 5 + kt;
            if (g + 2 < NG) {
                const unsigned short* Wp = Wtf + (size_t)(g + 2) * PLANE;
                bc2[0] = *(const bf16x8*)(Wp + boff0);
                bc2[1] = *(const bf16x8*)(Wp + boff1);
            }
            bf16x8 af[5];
#pragma unroll
            for (int i = 0; i < 5; ++i)
                af[i] = *(const bf16x8*)(Asb + (i * 16 + r16) * AROWSH + (kt * 4 + q) * 8);

            // gather-READ slot kt: single b128 from the 16B-stride table;
            // issued with this kt's af reads — the MFMA's counted lgkm wait
            // only covers af, leaving the gather outstanding.
            if (kt < 4 && stg && sact[kt])
                gr[kt] = *(const uint4*)(tableL + xv[kt] * 8);

#pragma unroll
            for (int i = 0; i < 5; ++i) {
                acc[i][0] = __builtin_amdgcn_mfma_f32_16x16x32_bf16(af[i], bc0[0], acc[i][0], 0, 0, 0);
                acc[i][1] = __builtin_amdgcn_mfma_f32_16x16x32_bf16(af[i], bc0[1], acc[i][1], 0, 0, 0);
            }
            bc0[0] = bc1[0]; bc0[1] = bc1[1];
            bc1[0] = bc2[0]; bc1[1] = bc2[1];

            // gather-WRITE slot kt-1: data arrived a full kt ago -> no stall;
            // kt's in-order lgkm traffic already drained the read.
            if (kt >= 1 && stg && sact[kt - 1])
                *(uint4*)(dstS + loff[kt - 1]) = gr[kt - 1];
        }
#pragma unroll
        for (int l = 0; l < 4; ++l) xv[l] = xn[l];
        LDS_BARRIER();
        buf ^= 1;
    }

    // ---- epilogue: gate + per-batch max in registers, atomicMax flush ----
    // C/D layout: col = lane&15 (n), row = q*4 + reg (m).
    const float b1v = b1[o], b2v = b2[o];
    float cur = 0.0f;
    int curb  = (m0 + q * 4) / TWIN;
#pragma unroll
    for (int i = 0; i < 5; ++i) {
#pragma unroll
        for (int rg = 0; rg < 4; ++rg) {
            const int row = m0 + i * 16 + q * 4 + rg;
            if (row < MROWS) {
                const int bb = row / TWIN;
                if (bb != curb) {
                    atomicMax((int*)&pool[curb * COUT + o], __float_as_int(cur));
                    cur = 0.0f; curb = bb;
                }
                const float c1 = acc[i][0][rg] + b1v;
                const float c2 = acc[i][1][rg] + b2v;
                const float g  = fmaxf(c1, 0.0f) / (1.0f + __expf(-c2));
                cur = fmaxf(cur, g);
            }
        }
    }
    atomicMax((int*)&pool[curb * COUT + o], __float_as_int(cur));

    // ---- fused head: last block to finish does the dense layers ----
    asm volatile("s_waitcnt vmcnt(0)" ::: "memory");
    __syncthreads();
    __shared__ int lastFlag;
    if (tid == 0) {
        int prev = __hip_atomic_fetch_add(cnt, 1, __ATOMIC_RELAXED, __HIP_MEMORY_SCOPE_AGENT);
        lastFlag = (prev == NTILE - 1) ? 1 : 0;
    }
    __syncthreads();
    if (!lastFlag) return;

    // reuse As as scratch: poolL[1024] + red[8][128]
    float* poolL = (float*)As;
    float* red   = poolL + BATCH * COUT;
    poolL[tid] = __int_as_float(
        __hip_atomic_load((int*)&pool[tid], __ATOMIC_RELAXED, __HIP_MEMORY_SCOPE_AGENT));
    poolL[tid + 512] = __int_as_float(
        __hip_atomic_load((int*)&pool[tid + 512], __ATOMIC_RELAXED, __HIP_MEMORY_SCOPE_AGENT));
    __syncthreads();

    if (tid < COUT) {
        const int j = tid;
        const float wj = wd2[j];
#pragma unroll
        for (int b = 0; b < BATCH; ++b) {
            float s = bd1[j];
            for (int i = 0; i < COUT; ++i) s += poolL[b * COUT + i] * wd1[j * COUT + i];
            red[b * COUT + j] = fmaxf(s, 0.0f) * wj;
        }
    }
    __syncthreads();
    if (tid < BATCH) {
        float s = 0.0f;
        for (int i = 0; i < COUT; ++i) s += red[tid * COUT + i];
        out[tid] = 1.0f / (1.0f + expf(-(s + bd2[0])));
    }
}

// ---------------- launch ----------------
extern "C" void kernel_launch(void* const* d_in, const int* in_sizes, int n_in,
                              void* d_out, int out_size, void* d_ws, size_t ws_size,
                              hipStream_t stream) {
    const int*   x   = (const int*)d_in[0];
    const float* emb = (const float*)d_in[1];
    const float* w1  = (const float*)d_in[2];
    const float* b1  = (const float*)d_in[3];
    const float* w2  = (const float*)d_in[4];
    const float* b2  = (const float*)d_in[5];
    const float* wd1 = (const float*)d_in[6];
    const float* bd1 = (const float*)d_in[7];
    const float* wd2 = (const float*)d_in[8];
    const float* bd2 = (const float*)d_in[9];
    float* out = (float*)d_out;

    unsigned short* Wtf  = (unsigned short*)((char*)d_ws + WTF_OFF);
    float*          pool = (float*)((char*)d_ws + POOL_OFF);
    int*            cnt  = (int*)((char*)d_ws + CNT_OFF);

    wprep_kernel<<<dim3(NDIM), dim3(256), 0, stream>>>(w1, w2, Wtf, pool, cnt);
    gemm_kernel<<<dim3(NTILE), dim3(512), 0, stream>>>(x, emb, Wtf, b1, b2, pool, cnt,
                                                       wd1, bd1, wd2, bd2, out);
}